// Round 10
// baseline (282.133 us; speedup 1.0000x reference)
//
#include <hip/hip_runtime.h>
#include <hip/hip_cooperative_groups.h>
namespace cg = cooperative_groups;

// Problem constants (from reference)
#define NB 64      // B
#define NC 23      // C
#define NL 26000   // L
#define ND 64      // D
#define NE 512     // E
#define NK 3       // K
#define FP4   (NL * NK / 4)         // 19500 float4 per (b,c) slice
#define CFP4  (NC * FP4)            // 448500 float4 per b slice
#define NBLK  1024                  // cooperative grid: exactly 4 blocks/CU
#define CHUNK 438                   // float4 per block; 438*1024 = 448512 >= 448500
#define GLSPAN 584                  // (c,l) rows per block = CHUNK*4/3
#define NBC (NB * NC)               // 1472 e-units

typedef float v4f __attribute__((ext_vector_type(4)));

// ---------------------------------------------------------------------------
// ONE cooperative kernel: phase0 e -> grid.sync -> phaseA a-chunk -> phaseB
// 64-b store loop.  No inter-kernel drains, no a workspace round-trip, store
// phase enters in near-lockstep (chip-wide ~7.2MB band sweep over b).
// ---------------------------------------------------------------------------
__global__ __launch_bounds__(256, 4) void coop_kernel(
    const float* __restrict__ eos_emb,   // [B][C][E]
    const int*   __restrict__ bin_ids,   // [C*L]
    const float* __restrict__ emb_table, // [V][D]
    const float* __restrict__ eos_W,     // [D][E]
    const float* __restrict__ eos_b,     // [D]
    const float* __restrict__ fc_W,      // [K][2D]
    const float* __restrict__ fc_b,      // [K]
    float* __restrict__ e_ws,            // [B*C][K] scratch
    float* __restrict__ out)             // [B][CFP4] float4
{
    const int bx = blockIdx.x;
    const int t  = threadIdx.x;
    const int q  = t & 3;
    const int d  = t >> 2;

    __shared__ v4f   xs4[NE / 4];        // 2 KB
    __shared__ float part[4][NK];
    __shared__ v4f   wb4[NK][ND / 4];    // 768 B
    __shared__ v4f   e4[3][NB][2];       // 6 KB
    __shared__ float a_lds[GLSPAN * 3];  // 7008 B

    // ---- Phase 0: e[b,c,k] for units bx, bx+1024 ----
    for (int bc = bx; bc < NBC; bc += NBLK) {
        if (t < NE / 4)
            xs4[t] = reinterpret_cast<const v4f*>(eos_emb + (size_t)bc * NE)[t];
        __syncthreads();
        const v4f* wrow = reinterpret_cast<const v4f*>(eos_W + (size_t)d * NE);
        v4f acc = (v4f)(0.f);
        #pragma unroll 8
        for (int j = 0; j < NE / 16; ++j) {
            const int idx = q + 4 * j;
            acc += wrow[idx] * xs4[idx];
        }
        float p = (acc.x + acc.y) + (acc.z + acc.w);
        p += __shfl_xor(p, 1, 64);
        p += __shfl_xor(p, 2, 64);
        const float eosd = p + eos_b[d];
        #pragma unroll
        for (int k = 0; k < NK; ++k) {
            float pk = eosd * fc_W[k * (2 * ND) + ND + d];   // We[k][d]
            pk += __shfl_xor(pk,  4, 64);
            pk += __shfl_xor(pk,  8, 64);
            pk += __shfl_xor(pk, 16, 64);
            pk += __shfl_xor(pk, 32, 64);
            if ((t & 63) == 0) part[t >> 6][k] = pk;
        }
        __syncthreads();
        if (t < NK)
            e_ws[(size_t)bc * NK + t] =
                part[0][t] + part[1][t] + part[2][t] + part[3][t] + fc_b[t];
        __syncthreads();
    }

    cg::this_grid().sync();

    // ---- Phase A: a-chunk -> LDS ----
    const int base  = bx * CHUNK;
    const int gl_lo = bx * GLSPAN;
    const int c_lo  = base / FP4;
    int c_hi = (base + CHUNK - 1) / FP4;
    if (c_hi >= NC) c_hi = NC - 1;

    if (t < NK * (ND / 4)) {
        const int k = t / (ND / 4), i = t % (ND / 4);
        wb4[k][i] = reinterpret_cast<const v4f*>(fc_W + (size_t)k * (2 * ND))[i];
    }
    for (int it = t; it < 3 * NB * 2; it += 256) {
        const int p   = it / (NB * 2);
        const int rem = it - p * (NB * 2);
        const int bl  = rem >> 1;
        const int ci  = rem & 1;
        const int c   = ci ? c_hi : c_lo;
        const float* ep = e_ws + ((size_t)bl * NC + c) * NK;
        const float e0 = ep[0], e1 = ep[1], e2 = ep[2];
        v4f v;
        if      (p == 0) { v.x = e0; v.y = e1; v.z = e2; v.w = e0; }
        else if (p == 1) { v.x = e1; v.y = e2; v.z = e0; v.w = e1; }
        else             { v.x = e2; v.y = e0; v.z = e1; v.w = e2; }
        e4[p][bl][ci] = v;
    }

    const int r = t >> 2;
    #pragma unroll
    for (int pass = 0; pass < 10; ++pass) {
        const int rl = pass * 64 + r;
        const int gl = gl_lo + rl;
        if (rl < GLSPAN && gl < NC * NL) {
            const int row = bin_ids[gl];
            const v4f* er = reinterpret_cast<const v4f*>(emb_table + (size_t)row * ND);
            v4f s0 = (v4f)(0.f), s1 = (v4f)(0.f), s2 = (v4f)(0.f);
            #pragma unroll
            for (int j = 0; j < 4; ++j) {
                const int idx = q + 4 * j;
                const v4f v = er[idx];
                s0 += v * wb4[0][idx];
                s1 += v * wb4[1][idx];
                s2 += v * wb4[2][idx];
            }
            float a0 = (s0.x + s0.y) + (s0.z + s0.w);
            float a1 = (s1.x + s1.y) + (s1.z + s1.w);
            float a2 = (s2.x + s2.y) + (s2.z + s2.w);
            a0 += __shfl_xor(a0, 1, 64); a0 += __shfl_xor(a0, 2, 64);
            a1 += __shfl_xor(a1, 1, 64); a1 += __shfl_xor(a1, 2, 64);
            a2 += __shfl_xor(a2, 1, 64); a2 += __shfl_xor(a2, 2, 64);
            if (q < NK) {
                const float val = (q == 0) ? a0 : (q == 1) ? a1 : a2;
                a_lds[rl * 3 + q] = val;
            }
        }
    }
    __syncthreads();

    // ---- Phase B: 64-b store loop ----
    const int c_split = (c_lo + 1) * FP4;
    const int f0  = base + t;
    const int p0  = f0 % 3;
    const int ci0 = (f0 >= c_split) ? 1 : 0;
    const bool v0 = (f0 < CFP4);
    v4f a0v = (v4f)(0.f);
    if (v0) a0v = *reinterpret_cast<const v4f*>(&a_lds[t * 4]);

    const int t1  = 256 + t;
    const bool has1 = (t1 < CHUNK);
    const int f1  = base + t1;
    const int p1  = has1 ? (f1 % 3) : 0;
    const int ci1 = (has1 && f1 >= c_split) ? 1 : 0;
    const bool v1 = has1 && (f1 < CFP4);
    v4f a1v = (v4f)(0.f);
    if (v1) a1v = *reinterpret_cast<const v4f*>(&a_lds[t1 * 4]);

    v4f* o4 = reinterpret_cast<v4f*>(out);
    size_t ob = 0;
    #pragma unroll 4
    for (int bl = 0; bl < NB; ++bl) {
        if (v0) {
            const v4f ev = e4[p0][bl][ci0];
            v4f o;
            o.x = fmaxf(a0v.x + ev.x, 0.f);
            o.y = fmaxf(a0v.y + ev.y, 0.f);
            o.z = fmaxf(a0v.z + ev.z, 0.f);
            o.w = fmaxf(a0v.w + ev.w, 0.f);
            o4[ob + f0] = o;
        }
        if (v1) {
            const v4f ev = e4[p1][bl][ci1];
            v4f o;
            o.x = fmaxf(a1v.x + ev.x, 0.f);
            o.y = fmaxf(a1v.y + ev.y, 0.f);
            o.z = fmaxf(a1v.z + ev.z, 0.f);
            o.w = fmaxf(a1v.w + ev.w, 0.f);
            o4[ob + f1] = o;
        }
        ob += CFP4;
    }
}

// ===========================================================================
// Fallback path (R7 structure) if cooperative launch is unavailable.
// ===========================================================================
#define R7CHUNK 3504
#define R7NCHUNK 128
#define R7NJ 14
#define R7GB 8

__global__ __launch_bounds__(256) void eos_e_kernel(
    const float* __restrict__ eos_emb, const float* __restrict__ eos_W,
    const float* __restrict__ eos_b, const float* __restrict__ fc_W,
    const float* __restrict__ fc_b, float* __restrict__ e_out)
{
    const int bc = blockIdx.x;
    const int t  = threadIdx.x;
    const int q  = t & 3;
    const int d  = t >> 2;

    __shared__ v4f xs4[NE / 4];
    if (t < NE / 4)
        xs4[t] = reinterpret_cast<const v4f*>(eos_emb + (size_t)bc * NE)[t];
    __syncthreads();

    const v4f* wrow = reinterpret_cast<const v4f*>(eos_W + (size_t)d * NE);
    v4f acc = (v4f)(0.f);
    #pragma unroll 8
    for (int j = 0; j < NE / 16; ++j) {
        const int idx = q + 4 * j;
        acc += wrow[idx] * xs4[idx];
    }
    float p = (acc.x + acc.y) + (acc.z + acc.w);
    p += __shfl_xor(p, 1, 64);
    p += __shfl_xor(p, 2, 64);
    const float eosd = p + eos_b[d];

    __shared__ float part[4][NK];
    #pragma unroll
    for (int k = 0; k < NK; ++k) {
        float pk = eosd * fc_W[k * (2 * ND) + ND + d];
        pk += __shfl_xor(pk,  4, 64);
        pk += __shfl_xor(pk,  8, 64);
        pk += __shfl_xor(pk, 16, 64);
        pk += __shfl_xor(pk, 32, 64);
        if ((t & 63) == 0) part[t >> 6][k] = pk;
    }
    __syncthreads();
    if (t < NK)
        e_out[(size_t)bc * NK + t] =
            part[0][t] + part[1][t] + part[2][t] + part[3][t] + fc_b[t];
}

__global__ __launch_bounds__(256) void a_kernel(
    const int* __restrict__ bin_ids, const float* __restrict__ emb_table,
    const float* __restrict__ fc_W, float* __restrict__ a_out)
{
    const int c = blockIdx.y;
    const int t = threadIdx.x;
    const int q = t & 3;
    const int r = t >> 2;
    const int l = blockIdx.x * 64 + r;

    __shared__ v4f wb4[NK][ND / 4];
    if (t < NK * (ND / 4)) {
        const int k = t / (ND / 4), i = t % (ND / 4);
        wb4[k][i] = reinterpret_cast<const v4f*>(fc_W + (size_t)k * (2 * ND))[i];
    }
    __syncthreads();
    if (l >= NL) return;

    const int row = bin_ids[(size_t)c * NL + l];
    const v4f* er = reinterpret_cast<const v4f*>(emb_table + (size_t)row * ND);

    v4f s0 = (v4f)(0.f), s1 = (v4f)(0.f), s2 = (v4f)(0.f);
    #pragma unroll
    for (int j = 0; j < 4; ++j) {
        const int idx = q + 4 * j;
        const v4f v = er[idx];
        s0 += v * wb4[0][idx];
        s1 += v * wb4[1][idx];
        s2 += v * wb4[2][idx];
    }
    float a0 = (s0.x + s0.y) + (s0.z + s0.w);
    float a1 = (s1.x + s1.y) + (s1.z + s1.w);
    float a2 = (s2.x + s2.y) + (s2.z + s2.w);
    a0 += __shfl_xor(a0, 1, 64); a0 += __shfl_xor(a0, 2, 64);
    a1 += __shfl_xor(a1, 1, 64); a1 += __shfl_xor(a1, 2, 64);
    a2 += __shfl_xor(a2, 1, 64); a2 += __shfl_xor(a2, 2, 64);

    if (q < NK) {
        const float val = (q == 0) ? a0 : (q == 1) ? a1 : a2;
        a_out[((size_t)c * NL + l) * NK + q] = val;
    }
}

__global__ __launch_bounds__(256) void bstream_kernel(
    const float* __restrict__ a_in, const float* __restrict__ e_in,
    float* __restrict__ out)
{
    const int bx = blockIdx.x;
    const int b0 = blockIdx.y * R7GB;
    const int t  = threadIdx.x;

    __shared__ v4f e4[3][NC][R7GB];
    for (int i = t; i < 3 * NC * R7GB; i += 256) {
        const int p   = i / (NC * R7GB);
        const int rem = i - p * (NC * R7GB);
        const int c   = rem / R7GB;
        const int bl  = rem - c * R7GB;
        const float* ep = e_in + ((size_t)(b0 + bl) * NC + c) * NK;
        const float e0 = ep[0], e1 = ep[1], e2 = ep[2];
        v4f v;
        if      (p == 0) { v.x = e0; v.y = e1; v.z = e2; v.w = e0; }
        else if (p == 1) { v.x = e1; v.y = e2; v.z = e0; v.w = e1; }
        else             { v.x = e2; v.y = e0; v.z = e1; v.w = e2; }
        e4[p][c][bl] = v;
    }
    __syncthreads();

    const int base = bx * R7CHUNK;
    const v4f* a4 = reinterpret_cast<const v4f*>(a_in);

    v4f        av[R7NJ];
    const v4f* eptr[R7NJ];
    bool       gj[R7NJ];
    #pragma unroll
    for (int j = 0; j < R7NJ; ++j) {
        const int fo = j * 256 + t;
        const int f  = base + fo;
        gj[j] = (fo < R7CHUNK) && (f < CFP4);
        const int fc = gj[j] ? f : 0;
        eptr[j] = &e4[fc % 3][fc / FP4][0];
        av[j]   = gj[j] ? a4[fc] : (v4f)(0.f);
    }

    v4f* o4 = reinterpret_cast<v4f*>(out);
    size_t obase = (size_t)b0 * CFP4 + base;
    #pragma unroll 2
    for (int bl = 0; bl < R7GB; ++bl) {
        #pragma unroll
        for (int j = 0; j < R7NJ; ++j) {
            if (gj[j]) {
                const v4f ev = eptr[j][bl];
                v4f o;
                o.x = fmaxf(av[j].x + ev.x, 0.f);
                o.y = fmaxf(av[j].y + ev.y, 0.f);
                o.z = fmaxf(av[j].z + ev.z, 0.f);
                o.w = fmaxf(av[j].w + ev.w, 0.f);
                o4[obase + j * 256 + t] = o;
            }
        }
        obase += CFP4;
    }
}

extern "C" void kernel_launch(void* const* d_in, const int* in_sizes, int n_in,
                              void* d_out, int out_size, void* d_ws, size_t ws_size,
                              hipStream_t stream) {
    const float* eos_emb   = (const float*)d_in[0];
    const int*   bin_ids   = (const int*)  d_in[1];
    const float* emb_table = (const float*)d_in[2];
    const float* eos_W     = (const float*)d_in[3];
    const float* eos_b     = (const float*)d_in[4];
    const float* fc_W      = (const float*)d_in[5];
    const float* fc_b      = (const float*)d_in[6];
    float*       out       = (float*)d_out;

    float*  e_ws = (float*)d_ws;
    const size_t a_off_bytes = 32768;
    float*  a_ws = (float*)((char*)d_ws + a_off_bytes);
    const size_t a_bytes = (size_t)NC * NL * NK * sizeof(float);

    bool coop_ok = false;
    if (ws_size >= a_off_bytes) {
        void* args[] = {(void*)&eos_emb, (void*)&bin_ids, (void*)&emb_table,
                        (void*)&eos_W, (void*)&eos_b, (void*)&fc_W, (void*)&fc_b,
                        (void*)&e_ws, (void*)&out};
        hipError_t err = hipLaunchCooperativeKernel((const void*)coop_kernel,
                                                    dim3(NBLK), dim3(256),
                                                    args, 0, stream);
        coop_ok = (err == hipSuccess);
    }

    if (!coop_ok && ws_size >= a_off_bytes + a_bytes) {
        eos_e_kernel<<<NB * NC, 256, 0, stream>>>(eos_emb, eos_W, eos_b, fc_W, fc_b, e_ws);
        dim3 grid_a((NL + 63) / 64, NC);
        a_kernel<<<grid_a, 256, 0, stream>>>(bin_ids, emb_table, fc_W, a_ws);
        dim3 grid_b(R7NCHUNK, NB / R7GB);
        bstream_kernel<<<grid_b, 256, 0, stream>>>(a_ws, e_ws, out);
    }
}

// Round 11
// 149.429 us; speedup vs baseline: 1.8881x; 1.8881x over previous
//
#include <hip/hip_runtime.h>

// Problem constants (from reference)
#define NB 64      // B
#define NC 23      // C
#define NL 26000   // L
#define ND 64      // D
#define NE 512     // E
#define NK 3       // K
#define FP4   (NL * NK / 4)         // 19500 float4 per (b,c) slice
#define CFP4  (NC * FP4)            // 448500 float4 per b slice

// store-kernel geometry: c-uniform chunks
#define S_CHUNK 1500                // float4 per chunk (24 KB); 13 * 1500 = 19500 = FP4
#define S_NCH   13                  // chunks per c
#define S_GB    8                   // b's per block
#define S_NJ    6                   // ceil(1500/256)

typedef float v4f __attribute__((ext_vector_type(4)));

// ---------------------------------------------------------------------------
// Kernel 1: e[b,c,k] = fc_b[k] + sum_d We[k,d]*(eos_b[d] + eos_emb[b,c,:]·eos_W[d,:])
// Quad-cooperative loads; two-stage reduction.  ~6 us.  (proven R6-R9)
// ---------------------------------------------------------------------------
__global__ __launch_bounds__(256) void eos_e_kernel(
    const float* __restrict__ eos_emb,  // [B][C][E]
    const float* __restrict__ eos_W,    // [D][E]
    const float* __restrict__ eos_b,    // [D]
    const float* __restrict__ fc_W,     // [K][2D]
    const float* __restrict__ fc_b,     // [K]
    float* __restrict__ e_out)          // [B*C][K]
{
    const int bc = blockIdx.x;
    const int t  = threadIdx.x;
    const int q  = t & 3;
    const int d  = t >> 2;

    __shared__ v4f xs4[NE / 4];
    if (t < NE / 4)
        xs4[t] = reinterpret_cast<const v4f*>(eos_emb + (size_t)bc * NE)[t];
    __syncthreads();

    const v4f* wrow = reinterpret_cast<const v4f*>(eos_W + (size_t)d * NE);
    v4f acc = (v4f)(0.f);
    #pragma unroll 8
    for (int j = 0; j < NE / 16; ++j) {
        const int idx = q + 4 * j;
        acc += wrow[idx] * xs4[idx];
    }
    float p = (acc.x + acc.y) + (acc.z + acc.w);
    p += __shfl_xor(p, 1, 64);
    p += __shfl_xor(p, 2, 64);
    const float eosd = p + eos_b[d];

    __shared__ float part[4][NK];
    #pragma unroll
    for (int k = 0; k < NK; ++k) {
        float pk = eosd * fc_W[k * (2 * ND) + ND + d];   // We[k][d]
        pk += __shfl_xor(pk,  4, 64);
        pk += __shfl_xor(pk,  8, 64);
        pk += __shfl_xor(pk, 16, 64);
        pk += __shfl_xor(pk, 32, 64);
        if ((t & 63) == 0) part[t >> 6][k] = pk;
    }
    __syncthreads();
    if (t < NK)
        e_out[(size_t)bc * NK + t] =
            part[0][t] + part[1][t] + part[2][t] + part[3][t] + fc_b[t];
}

// ---------------------------------------------------------------------------
// Kernel A: a[c,l,k] = dot(emb_table[bin_ids[c,l]], Wb[k]) -> workspace.
// Quad-cooperative gather, 9361 blocks for latency hiding.  (proven R6-R9)
// ---------------------------------------------------------------------------
__global__ __launch_bounds__(256) void a_kernel(
    const int*   __restrict__ bin_ids,    // [C][L]
    const float* __restrict__ emb_table,  // [V][D]
    const float* __restrict__ fc_W,       // [K][2D]
    float* __restrict__ a_out)            // [C][L][K]
{
    const int c = blockIdx.y;
    const int t = threadIdx.x;
    const int q = t & 3;
    const int r = t >> 2;
    const int l = blockIdx.x * 64 + r;

    __shared__ v4f wb4[NK][ND / 4];
    if (t < NK * (ND / 4)) {
        const int k = t / (ND / 4), i = t % (ND / 4);
        wb4[k][i] = reinterpret_cast<const v4f*>(fc_W + (size_t)k * (2 * ND))[i];
    }
    __syncthreads();
    if (l >= NL) return;

    const int row = bin_ids[(size_t)c * NL + l];
    const v4f* er = reinterpret_cast<const v4f*>(emb_table + (size_t)row * ND);

    v4f s0 = (v4f)(0.f), s1 = (v4f)(0.f), s2 = (v4f)(0.f);
    #pragma unroll
    for (int j = 0; j < 4; ++j) {
        const int idx = q + 4 * j;
        const v4f v = er[idx];
        s0 += v * wb4[0][idx];
        s1 += v * wb4[1][idx];
        s2 += v * wb4[2][idx];
    }
    float a0 = (s0.x + s0.y) + (s0.z + s0.w);
    float a1 = (s1.x + s1.y) + (s1.z + s1.w);
    float a2 = (s2.x + s2.y) + (s2.z + s2.w);
    a0 += __shfl_xor(a0, 1, 64); a0 += __shfl_xor(a0, 2, 64);
    a1 += __shfl_xor(a1, 1, 64); a1 += __shfl_xor(a1, 2, 64);
    a2 += __shfl_xor(a2, 1, 64); a2 += __shfl_xor(a2, 2, 64);

    if (q < NK) {
        const float val = (q == 0) ? a0 : (q == 1) ? a1 : a2;
        a_out[((size_t)c * NL + l) * NK + q] = val;
    }
}

// ---------------------------------------------------------------------------
// Kernel B (bstream2): high-occupancy store pass.
// Block = (c, chunk of 1500 float4, 8-b group).  2392 blocks (9.3/CU).
// __launch_bounds__(256,8) forces VGPR<=64 -> 32 waves/CU, doubling the
// chip-wide store issue rate vs R7's 16 waves/CU (the R10-counter theory).
// av[6]=24 VGPR; e-table [3][9] padded -> conflict-free LDS; no bounds math
// (chunks divide FP4 exactly; only j=5 has a t<220 guard).
// ---------------------------------------------------------------------------
__global__ __launch_bounds__(256, 8) void bstream2_kernel(
    const float* __restrict__ a_in,   // [C][FP4] float4
    const float* __restrict__ e_in,   // [B*C][K]
    float* __restrict__ out)          // [B][CFP4] float4
{
    const int bx = blockIdx.x;        // 0..298 = c*13 + ch
    const int c  = bx / S_NCH;
    const int ch = bx - c * S_NCH;
    const int b0 = blockIdx.y * S_GB;
    const int t  = threadIdx.x;

    __shared__ v4f e4[3][9];          // padded: banks distinct for the 3 phases
    if (t < 3 * S_GB) {
        const int p  = t >> 3;        // 0..2
        const int bl = t & 7;         // 0..7
        const float* ep = e_in + ((size_t)(b0 + bl) * NC + c) * NK;
        const float e0 = ep[0], e1 = ep[1], e2 = ep[2];
        v4f v;
        if      (p == 0) { v.x = e0; v.y = e1; v.z = e2; v.w = e0; }
        else if (p == 1) { v.x = e1; v.y = e2; v.z = e0; v.w = e1; }
        else             { v.x = e2; v.y = e0; v.z = e1; v.w = e2; }
        e4[p][bl] = v;
    }
    __syncthreads();

    const int base_c = ch * S_CHUNK;  // float4 offset within this c's slice
    const v4f* a4 = reinterpret_cast<const v4f*>(a_in) + (size_t)c * FP4 + base_c;

    v4f av[S_NJ];
    int ph[S_NJ];
    #pragma unroll
    for (int j = 0; j < S_NJ; ++j) {
        const int fo = j * 256 + t;
        av[j] = (v4f)(0.f);
        ph[j] = 0;
        if (fo < S_CHUNK) {
            av[j] = a4[fo];
            ph[j] = fo % 3;
        }
    }

    v4f* o4 = reinterpret_cast<v4f*>(out) + (size_t)b0 * CFP4 + (size_t)c * FP4 + base_c;
    #pragma unroll 2
    for (int bl = 0; bl < S_GB; ++bl) {
        #pragma unroll
        for (int j = 0; j < S_NJ; ++j) {
            const int fo = j * 256 + t;
            if (fo < S_CHUNK) {
                const v4f ev = e4[ph[j]][bl];
                v4f o;
                o.x = fmaxf(av[j].x + ev.x, 0.f);
                o.y = fmaxf(av[j].y + ev.y, 0.f);
                o.z = fmaxf(av[j].z + ev.z, 0.f);
                o.w = fmaxf(av[j].w + ev.w, 0.f);
                o4[fo] = o;
            }
        }
        o4 += CFP4;
    }
}

// ---------------------------------------------------------------------------
// Fused fallback for the case ws_size is too small.
// ---------------------------------------------------------------------------
__global__ __launch_bounds__(256) void decoder_fused_kernel(
    const int*   __restrict__ bin_ids,
    const float* __restrict__ emb_table,
    const float* __restrict__ fc_W,
    const float* __restrict__ e_in,
    float* __restrict__ out)
{
    const int c   = blockIdx.y;
    const int tid = threadIdx.x;
    const int l   = blockIdx.x * 256 + tid;

    __shared__ float wb[NK][ND];
    __shared__ float es[NB * NK];

    if (tid < NK * ND)
        wb[tid / ND][tid % ND] = fc_W[(tid / ND) * (2 * ND) + (tid % ND)];
    if (tid < NB * NK) {
        int b = tid / NK, k = tid % NK;
        es[tid] = e_in[((size_t)b * NC + c) * NK + k];
    }
    __syncthreads();
    if (l >= NL) return;

    const int row = bin_ids[(size_t)c * NL + l];
    const float4* er = reinterpret_cast<const float4*>(emb_table + (size_t)row * ND);
    const float4* w0 = reinterpret_cast<const float4*>(wb[0]);
    const float4* w1 = reinterpret_cast<const float4*>(wb[1]);
    const float4* w2 = reinterpret_cast<const float4*>(wb[2]);

    float a0 = 0.f, a1 = 0.f, a2 = 0.f;
    #pragma unroll
    for (int i = 0; i < ND / 4; ++i) {
        float4 v  = er[i];
        float4 p0 = w0[i], p1 = w1[i], p2 = w2[i];
        a0 += v.x * p0.x + v.y * p0.y + v.z * p0.z + v.w * p0.w;
        a1 += v.x * p1.x + v.y * p1.y + v.z * p1.z + v.w * p1.w;
        a2 += v.x * p2.x + v.y * p2.y + v.z * p2.z + v.w * p2.w;
    }

    size_t obase = ((size_t)c * NL + l) * NK;
    const size_t bstride = (size_t)NC * NL * NK;
    #pragma unroll 4
    for (int b = 0; b < NB; ++b) {
        const float e0 = es[b * NK + 0];
        const float e1 = es[b * NK + 1];
        const float e2 = es[b * NK + 2];
        out[obase + 0] = fmaxf(a0 + e0, 0.f);
        out[obase + 1] = fmaxf(a1 + e1, 0.f);
        out[obase + 2] = fmaxf(a2 + e2, 0.f);
        obase += bstride;
    }
}

extern "C" void kernel_launch(void* const* d_in, const int* in_sizes, int n_in,
                              void* d_out, int out_size, void* d_ws, size_t ws_size,
                              hipStream_t stream) {
    const float* eos_emb   = (const float*)d_in[0];
    const int*   bin_ids   = (const int*)  d_in[1];
    const float* emb_table = (const float*)d_in[2];
    const float* eos_W     = (const float*)d_in[3];
    const float* eos_b     = (const float*)d_in[4];
    const float* fc_W      = (const float*)d_in[5];
    const float* fc_b      = (const float*)d_in[6];
    float*       out       = (float*)d_out;

    // ws layout: [0, 32 KB) -> e (B*C*K floats); [32 KB, ...) -> a (C*L*K floats)
    float*  e_ws = (float*)d_ws;
    const size_t a_off_bytes = 32768;
    float*  a_ws = (float*)((char*)d_ws + a_off_bytes);
    const size_t a_bytes = (size_t)NC * NL * NK * sizeof(float);

    eos_e_kernel<<<NB * NC, 256, 0, stream>>>(eos_emb, eos_W, eos_b, fc_W, fc_b, e_ws);

    if (ws_size >= a_off_bytes + a_bytes) {
        dim3 grid_a((NL + 63) / 64, NC);            // 407 x 23 = 9361 blocks
        a_kernel<<<grid_a, 256, 0, stream>>>(bin_ids, emb_table, fc_W, a_ws);

        dim3 grid_b(S_NCH * NC, NB / S_GB);         // 299 x 8 = 2392 blocks (9.3/CU)
        bstream2_kernel<<<grid_b, 256, 0, stream>>>(a_ws, e_ws, out);
    } else {
        dim3 grid((NL + 255) / 256, NC);
        decoder_fused_kernel<<<grid, 256, 0, stream>>>(bin_ids, emb_table, fc_W, e_ws, out);
    }
}